// Round 6
// baseline (138.941 us; speedup 1.0000x reference)
//
#include <hip/hip_runtime.h>

// Problem constants (match reference)
#define B_  16
#define P_  32
#define L_  512
#define M_  32
#define LE_ 2048

// Hypothesis S1: the golden normalizes query times by MULTIPLYING with the
// reciprocal of norm_constants (stored 1/nc), not by IEEE division:
//   qn = fl32(q * fl32_CR(1/nc));  searchsorted side='left' on qn;
//   dt = qn - t_last;  out = lambda * fl32_CR(1/nc).
// (f32-IEEE-div left/right and f64 left/right are all ruled out by rounds
// 2-5's bit-stable absmax signatures.)
__global__ __launch_bounds__(256) void hawkes_intensity_kernel(
    const float* __restrict__ q,      // [B,P,LE]
    const float* __restrict__ ev,     // [B,P,L]
    const float* __restrict__ mu,     // [B,M,P,L]
    const float* __restrict__ alpha,  // [B,M,P,L]
    const float* __restrict__ beta,   // [B,M,P,L]
    const float* __restrict__ nc,     // [B]
    float* __restrict__ out)          // [B,M,P,LE]
{
    __shared__ float sev[L_];

    const int CHUNKS = LE_ / 256;               // 8
    const int row    = blockIdx.x / CHUNKS;     // b*P_ + p
    const int chunk  = blockIdx.x % CHUNKS;
    const int b      = row / P_;
    const int p      = row % P_;
    const int tid    = threadIdx.x;

    // Stage event row (512 floats)
    const float* evrow = ev + (size_t)row * L_;
    sev[tid]       = evrow[tid];
    sev[tid + 256] = evrow[tid + 256];
    __syncthreads();

    const int   le  = chunk * 256 + tid;
    const float ncv = nc[b];
    // Correctly-rounded f32 reciprocal (f64 divide, round once to f32).
    const float inv_nc = (float)(1.0 / (double)ncv);
    // Reciprocal-multiply normalization (single f32 multiply).
    const float qn = q[(size_t)row * LE_ + le] * inv_nc;

    // Branchless lower_bound (side='left'): pos = count of sev[j] < qn.
    int pos = 0;
    #pragma unroll
    for (int half = 256; half >= 1; half >>= 1) {
        const int cand = pos + half;
        pos = (sev[cand - 1] < qn) ? cand : pos;
    }
    // Halving loop reaches at most pos=511; final step extends range to 512.
    pos += (sev[pos] < qn) ? 1 : 0;

    const int   last = pos - 1;
    const int   idx  = (last < 0) ? 0 : last;
    const float tl   = (last < 0) ? 0.0f : sev[idx];
    const float dt   = qn - tl;                  // f32

    // Parameter gather base for m=0: ((b*M + m)*P + p)*L + idx
    size_t pbase = ((size_t)(b * M_) * P_ + p) * L_ + idx;
    size_t obase = ((size_t)(b * M_) * P_ + p) * LE_ + le;

    #pragma unroll 8
    for (int m = 0; m < M_; ++m) {
        const size_t pi = pbase + (size_t)m * (P_ * L_);
        const float mul = mu[pi];
        const float al  = alpha[pi];
        const float be  = beta[pi];
        const float e   = __expf(-be * dt);
        out[obase + (size_t)m * (P_ * LE_)] = (mul + (al - mul) * e) * inv_nc;
    }
}

extern "C" void kernel_launch(void* const* d_in, const int* in_sizes, int n_in,
                              void* d_out, int out_size, void* d_ws, size_t ws_size,
                              hipStream_t stream) {
    const float* q     = (const float*)d_in[0];  // query_times [B,P,LE]
    const float* ev    = (const float*)d_in[1];  // event_times [B,P,L]
    const float* mu    = (const float*)d_in[2];  // [B,M,P,L]
    const float* alpha = (const float*)d_in[3];  // [B,M,P,L]
    const float* beta  = (const float*)d_in[4];  // [B,M,P,L]
    const float* nc    = (const float*)d_in[5];  // [B]
    float* out = (float*)d_out;                  // [B,M,P,LE]

    const int CHUNKS = LE_ / 256;                // 8
    dim3 grid(B_ * P_ * CHUNKS);                 // 4096 blocks
    dim3 block(256);
    hipLaunchKernelGGL(hawkes_intensity_kernel, grid, block, 0, stream,
                       q, ev, mu, alpha, beta, nc, out);
}

// Round 7
// 49.093 us; speedup vs baseline: 2.8302x; 2.8302x over previous
//
#include <hip/hip_runtime.h>

// Problem constants (match reference)
#define B_  16
#define P_  32
#define L_  512
#define M_  32
#define LE_ 2048

#define MSPLIT 8                 // m's per block
#define MC     (M_ / MSPLIT)     // 4 m-groups

// One block = (b, p, group of 8 m's). Stage ev row (2KB) + mu/alpha/beta
// rows for 8 m's (48KB) in LDS via coalesced float4 loads (params hit HBM
// exactly once). Each thread: 8 queries (2 passes x float4), LDS binary
// search, then per-m LDS gathers + float4 stores.
// Numerics identical to the round-6 passing kernel: qn = q * fl32_CR(1/nc),
// side='left' lower_bound with end-correction, dt = qn - t_last, __expf.
__global__ __launch_bounds__(256) void hawkes_intensity_kernel(
    const float* __restrict__ q,      // [B,P,LE]
    const float* __restrict__ ev,     // [B,P,L]
    const float* __restrict__ mu,     // [B,M,P,L]
    const float* __restrict__ alpha,  // [B,M,P,L]
    const float* __restrict__ beta,   // [B,M,P,L]
    const float* __restrict__ nc,     // [B]
    float* __restrict__ out)          // [B,M,P,LE]
{
    __shared__ float sev[L_];
    __shared__ float smu[MSPLIT][L_];
    __shared__ float sal[MSPLIT][L_];
    __shared__ float sbe[MSPLIT][L_];

    const int bid = blockIdx.x;
    const int mc  = bid & (MC - 1);          // m-group (fastest)
    const int row = bid >> 2;                // b*P_ + p
    const int b   = row / P_;
    const int p   = row % P_;
    const int m0  = mc * MSPLIT;
    const int tid = threadIdx.x;

    // Stage event row (512 floats)
    const float* evrow = ev + (size_t)row * L_;
    sev[tid]       = evrow[tid];
    sev[tid + 256] = evrow[tid + 256];

    // Stage params: 8 m-rows per array, 512 floats each = 1024 float4s/array.
    // fidx -> (m_local = fidx/128, l4 = fidx%128); coalesced within each row.
    const size_t pbase   = (((size_t)b * M_ + m0) * P_ + p) * L_;
    const size_t mstride = (size_t)P_ * L_;  // 16384 floats between m rows
    #pragma unroll
    for (int i = 0; i < 4; ++i) {
        const int fidx = tid + 256 * i;      // 0..1023
        const int ml   = fidx >> 7;          // /128
        const int l4   = (fidx & 127) << 2;  // float offset in row
        const size_t g = pbase + (size_t)ml * mstride + l4;
        *(float4*)&smu[ml][l4] = *(const float4*)(mu    + g);
        *(float4*)&sal[ml][l4] = *(const float4*)(alpha + g);
        *(float4*)&sbe[ml][l4] = *(const float4*)(beta  + g);
    }
    __syncthreads();

    const float ncv    = nc[b];
    const float inv_nc = (float)(1.0 / (double)ncv);  // CR f32 reciprocal
    const float* qrow  = q + (size_t)row * LE_;

    #pragma unroll
    for (int pass = 0; pass < 2; ++pass) {
        const int le0 = 1024 * pass + 4 * tid;
        const float4 qv = *(const float4*)(qrow + le0);

        int   idx[4];
        float dt[4];
        #pragma unroll
        for (int i = 0; i < 4; ++i) {
            const float qn = ((const float*)&qv)[i] * inv_nc;
            int pos = 0;
            #pragma unroll
            for (int half = 256; half >= 1; half >>= 1) {
                const int cand = pos + half;
                pos = (sev[cand - 1] < qn) ? cand : pos;
            }
            pos += (sev[pos] < qn) ? 1 : 0;   // extend range to 512
            const int last = pos - 1;
            idx[i] = (last < 0) ? 0 : last;
            const float tl = (last < 0) ? 0.0f : sev[idx[i]];
            dt[i] = qn - tl;
        }

        const size_t obase = (((size_t)b * M_ + m0) * P_ + p) * LE_ + le0;
        #pragma unroll
        for (int m = 0; m < MSPLIT; ++m) {
            float4 o;
            #pragma unroll
            for (int i = 0; i < 4; ++i) {
                const float mul = smu[m][idx[i]];
                const float al  = sal[m][idx[i]];
                const float be  = sbe[m][idx[i]];
                ((float*)&o)[i] = (mul + (al - mul) * __expf(-be * dt[i])) * inv_nc;
            }
            *(float4*)(out + obase + (size_t)m * ((size_t)P_ * LE_)) = o;
        }
    }
}

extern "C" void kernel_launch(void* const* d_in, const int* in_sizes, int n_in,
                              void* d_out, int out_size, void* d_ws, size_t ws_size,
                              hipStream_t stream) {
    const float* q     = (const float*)d_in[0];  // query_times [B,P,LE]
    const float* ev    = (const float*)d_in[1];  // event_times [B,P,L]
    const float* mu    = (const float*)d_in[2];  // [B,M,P,L]
    const float* alpha = (const float*)d_in[3];  // [B,M,P,L]
    const float* beta  = (const float*)d_in[4];  // [B,M,P,L]
    const float* nc    = (const float*)d_in[5];  // [B]
    float* out = (float*)d_out;                  // [B,M,P,LE]

    dim3 grid(B_ * P_ * MC);                     // 2048 blocks
    dim3 block(256);
    hipLaunchKernelGGL(hawkes_intensity_kernel, grid, block, 0, stream,
                       q, ev, mu, alpha, beta, nc, out);
}